// Round 4
// baseline (243.630 us; speedup 1.0000x reference)
//
#include <hip/hip_runtime.h>

// HarmonicMixing closed form per row of D=1024 channels (gathers read ORIGINAL x):
//   out[j] = x[j]
//          + sum_{o=1..3, s=2^o} ( [j%s==0] * sig(uw[o]) * x[j/s]        (up)
//                                 + [1<=j<D/s] * sig(dw[o]) * W_s[j] )   (down)
// W_s[j] = sum(x[j*s .. j*s+s-1]):  S1=pairsum(x), S2=pairsum(S1), S3=pairsum(S2).
//
// R1: strided LDS reads -> 16/32-way conflicts; fixed via register pair-sums +
//     stride-1 LDS (kept).
// R3: MLP-4 + nontemporal + 1 barrier/16KB: NULL (kernel pinned ~62us / 4.3 TB/s).
// R5/R6 (this; R6 = infra-failed resubmit): remaining gap to the 6.3 TB/s copy
//     ceiling is structural: one-shot blocks + __syncthreads (drains vmcnt(0))
//     kill cross-iteration load overlap. Restructure:
//     (a) wave-per-row: lane l owns floats {256m+4l..+3}, m=0..3. S1/S2/S3 are
//         then REGISTER-LOCAL per lane; producer wave == consumer wave =>
//         wave-synchronous LDS, ZERO __syncthreads. Global stays coalesced
//         (contiguous 1KB/wave per instr); LDS stays stride-1 / 2-way (free).
//     (b) persistent grid-stride (1792 blocks = 7/CU), copy-ubench style.
//     (c) register double-buffer: next row's loads in flight during current
//         row's compute+store (no barrier anywhere to drain them).

constexpr int D = 1024;

using f4 = __attribute__((ext_vector_type(4))) float;  // native vec for nontemporal builtins

__global__ __launch_bounds__(256, 7) void harmonic_kernel(
    const float* __restrict__ x,
    const float* __restrict__ uwp,
    const float* __restrict__ dwp,
    float* __restrict__ out,
    const int n_rows)
{
    // Per-WAVE private scratch (wave-synchronous: no cross-wave traffic, no barrier).
    __shared__ float rowlo[4][512];  // x[0..511] of this wave's row
    __shared__ float S1lds[4][512];
    __shared__ float S2lds[4][256];  // S3 derived on the fly: S3[j]=S2[2j]+S2[2j+1]

    const int t = threadIdx.x;
    const int w = t >> 6;   // wave 0..3
    const int l = t & 63;   // lane

    const float uw0 = 1.f / (1.f + __expf(-uwp[0]));
    const float uw1 = 1.f / (1.f + __expf(-uwp[1]));
    const float uw2 = 1.f / (1.f + __expf(-uwp[2]));
    const float dw0 = 1.f / (1.f + __expf(-dwp[0]));
    const float dw1 = 1.f / (1.f + __expf(-dwp[1]));
    const float dw2 = 1.f / (1.f + __expf(-dwp[2]));

    float* const RL = rowlo[w];
    float* const P1 = S1lds[w];
    float* const P2 = S2lds[w];

    auto loadrow = [&](f4* v, const float* p) {
#pragma unroll
        for (int m = 0; m < 4; ++m)
            v[m] = __builtin_nontemporal_load(reinterpret_cast<const f4*>(p + 256 * m));
    };

    // Process one row held in v[0..3] (chunk m = floats 256m+4l .. +3), store to po.
    auto process = [&](f4* v, float* po) {
        // ---- stage (same wave consumes; LDS pipe is in-order per wave) ----
        *reinterpret_cast<f4*>(&RL[4 * l])       = v[0];   // x[0..255]
        *reinterpret_cast<f4*>(&RL[256 + 4 * l]) = v[1];   // x[256..511]
#pragma unroll
        for (int m = 0; m < 4; ++m) {
            const float s1a = v[m].x + v[m].y;             // S1[128m+2l]
            const float s1b = v[m].z + v[m].w;             // S1[128m+2l+1]
            *reinterpret_cast<float2*>(&P1[128 * m + 2 * l]) = make_float2(s1a, s1b);
            P2[64 * m + l] = s1a + s1b;                    // S2[64m+l]
        }

        // ---- up: j = 256m + 4l + k ----
#pragma unroll
        for (int m = 0; m < 4; ++m) {
            // o=1 (j even): k=0 -> x[128m+2l], k=2 -> x[128m+2l+1]
            const float2 u = *reinterpret_cast<const float2*>(&RL[128 * m + 2 * l]);
            v[m].x += uw0 * u.x;
            v[m].z += uw0 * u.y;
            // o=2 (j%4==0): k=0 -> x[64m+l]
            v[m].x += uw1 * RL[64 * m + l];
            // o=3 (j%8==0): k=0 and l even -> x[32m+l/2]
            if ((l & 1) == 0) v[m].x += uw2 * RL[32 * m + (l >> 1)];
        }

        // ---- down o=1: j<512 -> chunks 0,1 (stride-1 b128) ----
#pragma unroll
        for (int m = 0; m < 2; ++m) {
            const f4 a = *reinterpret_cast<const f4*>(&P1[256 * m + 4 * l]);
            if (m > 0 || l > 0) v[m].x += dw0 * a.x;       // j=0 excluded
            v[m].y += dw0 * a.y;
            v[m].z += dw0 * a.z;
            v[m].w += dw0 * a.w;
        }
        // ---- down o=2: j<256 -> chunk 0 ----
        {
            const f4 b = *reinterpret_cast<const f4*>(&P2[4 * l]);
            if (l > 0) v[0].x += dw1 * b.x;
            v[0].y += dw1 * b.y;
            v[0].z += dw1 * b.z;
            v[0].w += dw1 * b.w;
        }
        // ---- down o=3: j<128 -> chunk 0, lanes<32; S3[j]=S2[2j]+S2[2j+1] ----
        if (l < 32) {
            const f4 p = *reinterpret_cast<const f4*>(&P2[8 * l]);
            const f4 q = *reinterpret_cast<const f4*>(&P2[8 * l + 4]);
            if (l > 0) v[0].x += dw2 * (p.x + p.y);
            v[0].y += dw2 * (p.z + p.w);
            v[0].z += dw2 * (q.x + q.y);
            v[0].w += dw2 * (q.z + q.w);
        }

        // ---- store ----
#pragma unroll
        for (int m = 0; m < 4; ++m)
            __builtin_nontemporal_store(v[m], reinterpret_cast<f4*>(po + 256 * m));
    };

    // ---- persistent grid-stride over rows, register double-buffered ----
    const long long rowstep = 4LL * gridDim.x;   // 4 waves/block advance together
    long long row = 4LL * blockIdx.x + w;
    if (row >= n_rows) return;

    f4 vA[4], vB[4];
    loadrow(vA, x + row * D + 4 * l);
    for (;;) {
        const long long rowB = row + rowstep;
        const bool hasB = rowB < n_rows;
        if (hasB) loadrow(vB, x + rowB * D + 4 * l);     // in flight during process(vA)
        process(vA, out + row * D + 4 * l);
        if (!hasB) return;

        const long long rowC = rowB + rowstep;
        const bool hasC = rowC < n_rows;
        if (hasC) loadrow(vA, x + rowC * D + 4 * l);     // in flight during process(vB)
        process(vB, out + rowB * D + 4 * l);
        if (!hasC) return;
        row = rowC;
    }
}

extern "C" void kernel_launch(void* const* d_in, const int* in_sizes, int n_in,
                              void* d_out, int out_size, void* d_ws, size_t ws_size,
                              hipStream_t stream) {
    const float* x   = (const float*)d_in[0];
    const float* uwp = (const float*)d_in[1];
    const float* dwp = (const float*)d_in[2];
    float* out = (float*)d_out;
    const int n_rows = in_sizes[0] / D;                  // 8 * 4096 = 32768
    int ngroups = (n_rows + 3) / 4;
    int nb = ngroups < 1792 ? ngroups : 1792;            // 7 blocks/CU x 256 CU, grid-stride
    harmonic_kernel<<<nb, 256, 0, stream>>>(x, uwp, dwp, out, n_rows);
}

// Round 5
// 222.326 us; speedup vs baseline: 1.0958x; 1.0958x over previous
//
#include <hip/hip_runtime.h>

// HarmonicMixing closed form per row of D=1024 channels (gathers read ORIGINAL x):
//   out[j] = x[j]
//          + sum_{o=1..3, s=2^o} ( [j%s==0] * sig(uw[o]) * x[j/s]        (up)
//                                 + [1<=j<D/s] * sig(dw[o]) * W_s[j] )   (down)
// W_s[j] = sum(x[j*s .. j*s+s-1]):  S1=pairsum(x), S2=pairsum(S1), S3=pairsum(S2).
//
// Structure matrix (kernel-portion times):
//   R0  one-shot x block-barrier          : ~62 us   <- prior best
//   R3  + MLP4 + nontemporal              : null
//   R5  persistent x zero-barrier         : ~80 us   REGRESSION — per-wave serial
//       chains beat by hardware wave-swap; wave-private mapping itself verified OK.
//   R7 (this): the untested cell — ONE-SHOT x ZERO-BARRIER. Each wave owns one
//       row (lane l owns floats {256m+4l..+3}); S1/S2 pair-sums are lane-local;
//       producer wave == consumer wave => wave-synchronous LDS, no __syncthreads,
//       so no block-wide vmcnt(0) drain locking 4 waves to the slowest load.
//       Hardware swaps 8 independent blocks/CU — that is the pipeline.

constexpr int D = 1024;

using f4 = __attribute__((ext_vector_type(4))) float;  // native vec for nontemporal builtins

__global__ __launch_bounds__(256) void harmonic_kernel(
    const float* __restrict__ x,
    const float* __restrict__ uwp,
    const float* __restrict__ dwp,
    float* __restrict__ out,
    const int n_rows)
{
    // Per-WAVE private scratch (wave-synchronous: no cross-wave traffic, no barrier).
    __shared__ float rowlo[4][512];  // x[0..511] of this wave's row
    __shared__ float S1lds[4][512];
    __shared__ float S2lds[4][256];  // S3 derived on the fly: S3[j]=S2[2j]+S2[2j+1]

    const int t = threadIdx.x;
    const int w = t >> 6;   // wave 0..3
    const int l = t & 63;   // lane

    const long long row = 4LL * blockIdx.x + w;   // one row per wave, one-shot
    if (row >= n_rows) return;

    const float uw0 = 1.f / (1.f + __expf(-uwp[0]));
    const float uw1 = 1.f / (1.f + __expf(-uwp[1]));
    const float uw2 = 1.f / (1.f + __expf(-uwp[2]));
    const float dw0 = 1.f / (1.f + __expf(-dwp[0]));
    const float dw1 = 1.f / (1.f + __expf(-dwp[1]));
    const float dw2 = 1.f / (1.f + __expf(-dwp[2]));

    float* const RL = rowlo[w];
    float* const P1 = S1lds[w];
    float* const P2 = S2lds[w];

    const float* px = x + row * D + 4 * l;
    float*       po = out + row * D + 4 * l;

    // ---- load: lane l owns chunks m: floats 256m + 4l .. +3 (coalesced 1KB/instr) ----
    f4 v[4];
#pragma unroll
    for (int m = 0; m < 4; ++m)
        v[m] = __builtin_nontemporal_load(reinterpret_cast<const f4*>(px + 256 * m));

    // ---- stage (same wave consumes; LDS pipe is in-order per wave, no barrier) ----
    *reinterpret_cast<f4*>(&RL[4 * l])       = v[0];   // x[0..255]
    *reinterpret_cast<f4*>(&RL[256 + 4 * l]) = v[1];   // x[256..511]
#pragma unroll
    for (int m = 0; m < 4; ++m) {
        const float s1a = v[m].x + v[m].y;             // S1[128m+2l]
        const float s1b = v[m].z + v[m].w;             // S1[128m+2l+1]
        *reinterpret_cast<float2*>(&P1[128 * m + 2 * l]) = make_float2(s1a, s1b);
        P2[64 * m + l] = s1a + s1b;                    // S2[64m+l]
    }

    // ---- up: j = 256m + 4l + k ----
#pragma unroll
    for (int m = 0; m < 4; ++m) {
        // o=1 (j even): k=0 -> x[128m+2l], k=2 -> x[128m+2l+1]
        const float2 u = *reinterpret_cast<const float2*>(&RL[128 * m + 2 * l]);
        v[m].x += uw0 * u.x;
        v[m].z += uw0 * u.y;
        // o=2 (j%4==0): k=0 -> x[64m+l]
        v[m].x += uw1 * RL[64 * m + l];
        // o=3 (j%8==0): k=0 and l even -> x[32m+l/2]
        if ((l & 1) == 0) v[m].x += uw2 * RL[32 * m + (l >> 1)];
    }

    // ---- down o=1: j<512 -> chunks 0,1 (stride-1 b128) ----
#pragma unroll
    for (int m = 0; m < 2; ++m) {
        const f4 a = *reinterpret_cast<const f4*>(&P1[256 * m + 4 * l]);
        if (m > 0 || l > 0) v[m].x += dw0 * a.x;       // j=0 excluded
        v[m].y += dw0 * a.y;
        v[m].z += dw0 * a.z;
        v[m].w += dw0 * a.w;
    }
    // ---- down o=2: j<256 -> chunk 0 ----
    {
        const f4 b = *reinterpret_cast<const f4*>(&P2[4 * l]);
        if (l > 0) v[0].x += dw1 * b.x;
        v[0].y += dw1 * b.y;
        v[0].z += dw1 * b.z;
        v[0].w += dw1 * b.w;
    }
    // ---- down o=3: j<128 -> chunk 0, lanes<32; S3[j]=S2[2j]+S2[2j+1] ----
    if (l < 32) {
        const f4 p = *reinterpret_cast<const f4*>(&P2[8 * l]);
        const f4 q = *reinterpret_cast<const f4*>(&P2[8 * l + 4]);
        if (l > 0) v[0].x += dw2 * (p.x + p.y);
        v[0].y += dw2 * (p.z + p.w);
        v[0].z += dw2 * (q.x + q.y);
        v[0].w += dw2 * (q.z + q.w);
    }

    // ---- store and exit; hardware swaps in the next block ----
#pragma unroll
    for (int m = 0; m < 4; ++m)
        __builtin_nontemporal_store(v[m], reinterpret_cast<f4*>(po + 256 * m));
}

extern "C" void kernel_launch(void* const* d_in, const int* in_sizes, int n_in,
                              void* d_out, int out_size, void* d_ws, size_t ws_size,
                              hipStream_t stream) {
    const float* x   = (const float*)d_in[0];
    const float* uwp = (const float*)d_in[1];
    const float* dwp = (const float*)d_in[2];
    float* out = (float*)d_out;
    const int n_rows = in_sizes[0] / D;                  // 8 * 4096 = 32768
    const int nb = (n_rows + 3) / 4;                     // 4 waves/block, 1 row/wave
    harmonic_kernel<<<nb, 256, 0, stream>>>(x, uwp, dwp, out, n_rows);
}